// Round 17
// baseline (1180.537 us; speedup 1.0000x reference)
//
#include <hip/hip_runtime.h>
#include <math.h>

#define DEVI static __device__ __forceinline__

typedef unsigned short u16;
typedef __attribute__((ext_vector_type(8))) short short8;
typedef __attribute__((ext_vector_type(4))) float f32x4;

DEVI float bf2f(u16 u) { union { float f; unsigned int i; } c; c.i = ((unsigned int)u) << 16; return c.f; }
DEVI u16 f2bf(float f) {
  union { float f; unsigned int i; } c; c.f = f;
  unsigned int r = c.i + 0x7FFFu + ((c.i >> 16) & 1u);
  return (u16)(r >> 16);
}

DEVI float ftanh(float x) {
  float e = __expf(2.f * x);
  return 1.f - 2.f * __builtin_amdgcn_rcpf(e + 1.f);
}

// async global->LDS, 16B per lane. LDS base must be wave-uniform; HW adds lane*16B.
DEVI void gld16(const u16* g, u16* l) {
  __builtin_amdgcn_global_load_lds((const __attribute__((address_space(1))) unsigned int*)g,
                                   (__attribute__((address_space(3))) unsigned int*)l, 16, 0, 0);
}

#define BB 64
#define LQN 128
#define LKN 1024
#define EN 768
#define HN 6
#define HDN 128
#define D2N 64
#define EPSV 1e-5f

// prep role block counts
#define NB_CONV 3072
#define NB_TW5 2880
#define NB_WAB 16
#define NB_UV 96
#define NB_PQ 64
#define NB_MS 64
#define NB_PREP (NB_CONV + NB_TW5 + NB_WAB + NB_UV + NB_PQ + NB_MS)

// ---------------------------------------------------------------------------
// Fused prep: conv(k_feats->kf bf16) | transpose 5x768^2 (L1 g-fold) |
// transpose Wab | uv vectors | poolq | msum.  All roles independent.
__global__ __launch_bounds__(256) void prep_kernel(
    const float* __restrict__ k_feats, u16* __restrict__ kf,
    const float* __restrict__ Wk, const float* __restrict__ Wv2,
    const float* __restrict__ Wbi, const float* __restrict__ lnb_g,
    u16* __restrict__ WkvT, u16* __restrict__ WbiT,
    const float* __restrict__ Wab, u16* __restrict__ WabT,
    const float* __restrict__ lnb_b, const float* __restrict__ bkL1,
    const float* __restrict__ bv2L1, float* __restrict__ uvec,
    float* __restrict__ vbvec,
    const float* __restrict__ qf, const float* __restrict__ qm,
    float* __restrict__ q_cur, float* __restrict__ feats,
    const float* __restrict__ km, float* __restrict__ msum) {
  __shared__ float ls[1056];   // union scratch: transpose tile / uv partials / msum red
  int b = blockIdx.x, t = threadIdx.x;

  if (b < NB_CONV) {  // fp32 -> bf16, grid-strided, short8 stores
    size_t n8 = (size_t)BB * LKN * EN / 8;
    for (size_t i = (size_t)b * 256 + t; i < n8; i += (size_t)NB_CONV * 256) {
      float4 a = ((const float4*)k_feats)[2 * i];
      float4 c = ((const float4*)k_feats)[2 * i + 1];
      short8 o;
      o[0] = (short)f2bf(a.x); o[1] = (short)f2bf(a.y); o[2] = (short)f2bf(a.z); o[3] = (short)f2bf(a.w);
      o[4] = (short)f2bf(c.x); o[5] = (short)f2bf(c.y); o[6] = (short)f2bf(c.z); o[7] = (short)f2bf(c.w);
      *(short8*)&kf[i * 8] = o;
    }
    return;
  }
  b -= NB_CONV;
  if (b < NB_TW5) {  // transpose+cvt 768x768: z = which matrix
    int z = b / 576, rem = b % 576;
    int kb = (rem / 24) * 32, nb = (rem % 24) * 32;
    const float* src;
    u16* dst;
    bool fold = (z == 1) || (z == 3);
    if (z < 2) { src = Wk + (size_t)z * EN * EN; dst = WkvT + (size_t)z * 1536 * EN; }
    else if (z < 4) { src = Wv2 + (size_t)(z - 2) * EN * EN; dst = WkvT + (size_t)(z - 2) * 1536 * EN + (size_t)EN * EN; }
    else { src = Wbi + (size_t)EN * EN; dst = WbiT; }
    int tx = t & 31, ty = t >> 5;  // 32 x 8
    for (int j = 0; j < 32; j += 8) {
      float v = src[(size_t)(kb + ty + j) * EN + nb + tx];
      if (fold) v *= lnb_g[kb + ty + j];
      ls[(ty + j) * 33 + tx] = v;
    }
    __syncthreads();
    for (int j = 0; j < 32; j += 8)
      dst[(size_t)(nb + ty + j) * EN + kb + tx] = f2bf(ls[tx * 33 + ty + j]);
    return;
  }
  b -= NB_TW5;
  if (b < NB_WAB) {  // transpose+cvt Wab (HD x D2) -> WabT (D2 x HD), 2 layers
    int z = b / 8, rem = b % 8;
    int kb = (rem / 2) * 32, nb = (rem % 2) * 32;
    const float* src = Wab + (size_t)z * HDN * D2N;
    u16* dst = WabT + (size_t)z * D2N * HDN;
    int tx = t & 31, ty = t >> 5;
    for (int j = 0; j < 32; j += 8)
      ls[(ty + j) * 33 + tx] = src[(size_t)(kb + ty + j) * D2N + nb + tx];
    __syncthreads();
    for (int j = 0; j < 32; j += 8)
      dst[(size_t)(nb + ty + j) * HDN + kb + tx] = f2bf(ls[tx * 33 + ty + j]);
    return;
  }
  b -= NB_WAB;
  if (b < NB_UV) {  // u = g@W, vb = bb@W + bias for layer-1 Wk/Wv2
    float* pu = ls;            // [16][17]
    float* pv = ls + 272;      // [16][17]
    int col = t & 15, ks = t >> 4;
    int c = b * 16 + col;
    int part = c >= EN;
    int cc = part ? c - EN : c;  // EN is NOT a power of two - no mask tricks
    const float* W = (part ? Wv2 : Wk) + (size_t)EN * EN;  // layer-1 weights
    float u = 0.f, vb = 0.f;
    for (int k = ks * 48; k < ks * 48 + 48; ++k) {
      float w = W[(size_t)k * EN + cc];
      u += lnb_g[k] * w;
      vb += lnb_b[k] * w;
    }
    pu[ks * 17 + col] = u; pv[ks * 17 + col] = vb;
    __syncthreads();
    if (t < 16) {
      int c2 = b * 16 + t;
      int part2 = c2 >= EN;
      int cc2 = part2 ? c2 - EN : c2;
      float su = 0.f, sv = 0.f;
#pragma unroll
      for (int s = 0; s < 16; ++s) { su += pu[s * 17 + t]; sv += pv[s * 17 + t]; }
      sv += part2 ? bv2L1[cc2] : bkL1[cc2];
      uvec[c2] = su;
      vbvec[c2] = sv;
    }
    return;
  }
  b -= NB_UV;
  if (b < NB_PQ) {  // mean-pool q_feat -> q_cur + feats slot 0 (3 cols/thread)
    float s0 = 0.f, s1 = 0.f, s2 = 0.f, ms = 0.f;
    for (int l = 0; l < LQN; ++l) {
      float w = qm[b * LQN + l];
      const float* row = qf + ((size_t)b * LQN + l) * EN;
      s0 += row[t] * w; s1 += row[t + 256] * w; s2 += row[t + 512] * w;
      ms += w;
    }
    float inv = 1.f / ms;
    q_cur[(size_t)b * EN + t] = s0 * inv;
    q_cur[(size_t)b * EN + t + 256] = s1 * inv;
    q_cur[(size_t)b * EN + t + 512] = s2 * inv;
    feats[(size_t)b * 3 * EN + t] = s0 * inv;
    feats[(size_t)b * 3 * EN + t + 256] = s1 * inv;
    feats[(size_t)b * 3 * EN + t + 512] = s2 * inv;
    return;
  }
  b -= NB_PQ;
  {  // msum
    float s = 0.f;
    for (int l = t; l < LKN; l += 256) s += km[b * LKN + l];
    ls[t] = s; __syncthreads();
    for (int o = 128; o > 0; o >>= 1) { if (t < o) ls[t] += ls[t + o]; __syncthreads(); }
    if (t == 0) msum[b] = ls[0];
  }
}

// merged q-side projections: y-grid picks {Wq->qp}, {Wv1->v1}, or {Wbi->qpart}
__global__ __launch_bounds__(768) void qside2_kernel(
    const float* __restrict__ q_in,
    const float* __restrict__ W0, const float* __restrict__ b0,
    const float* __restrict__ g0, const float* __restrict__ bb0, float* __restrict__ o0,
    const float* __restrict__ W1, const float* __restrict__ b1,
    const float* __restrict__ g1, const float* __restrict__ bb1, float* __restrict__ o1,
    const float* __restrict__ W2, const float* __restrict__ b2, float* __restrict__ o2) {
  __shared__ float qs[EN];
  __shared__ float ys[EN];
  __shared__ float mh[HN], rh[HN];
  int t = threadIdx.x, b = blockIdx.x, which = blockIdx.y;
  const float* W = which == 0 ? W0 : (which == 1 ? W1 : W2);
  const float* bvec = which == 0 ? b0 : (which == 1 ? b1 : b2);
  qs[t] = q_in[(size_t)b * EN + t];
  __syncthreads();
  float acc = 0.f;
  for (int k = 0; k < EN; ++k) acc += qs[k] * W[(size_t)k * EN + t];
  if (which == 2) {  // qpart: no activation / GN
    o2[(size_t)b * EN + t] = acc + bvec[t];
    return;
  }
  const float* g = which ? g1 : g0;
  const float* bb = which ? bb1 : bb0;
  float* outp = which ? o1 : o0;
  float y = tanhf(acc + bvec[t]);
  ys[t] = y; __syncthreads();
  if (t < HN) {
    float s = 0.f, s2 = 0.f;
    for (int d = 0; d < HDN; ++d) { float v = ys[t * HDN + d]; s += v; s2 += v * v; }
    float m = s * (1.f / HDN), var = s2 * (1.f / HDN) - m * m;
    mh[t] = m; rh[t] = rsqrtf(var + EPSV);
  }
  __syncthreads();
  int h = t >> 7;
  outp[(size_t)b * EN + t] = (y - mh[h]) * rh[h] * g[t] + bb[t];
}

// ---------------------------------------------------------------------------
// Merged projection GEMM + fused "basic" attention GEMM.
// BARRIER-FREE K-loop: each wave stages its own 64x32 A and B slabs into a
// private 16KB double-buffered LDS region; sync is per-wave counted
// s_waitcnt vmcnt(8) only (no __syncthreads inside the K-loop).
// LNF=true (layer 1): A is pre-LN z; LN applied algebraically.
template <bool LNF>
__global__ __launch_bounds__(256, 2) void gemm_proj(
    const u16* __restrict__ A, const u16* __restrict__ BT,
    const float* __restrict__ bias_k, const float* __restrict__ g_k,
    const float* __restrict__ bb_k, const float* __restrict__ qp,
    const float* __restrict__ bias_v, const float* __restrict__ g_v,
    const float* __restrict__ bb_v, u16* __restrict__ out_v,
    const u16* __restrict__ Wab_g, const float* __restrict__ bab_g,
    const float* __restrict__ Wal_g, const float* __restrict__ bal_g,
    const float* __restrict__ kmask, float* __restrict__ s_out,
    float* __restrict__ pool_part,
    const float2* __restrict__ rowpart, const float* __restrict__ uvec,
    const float* __restrict__ vbvec) {
  const int K = EN;
  __shared__ __align__(16) u16 SM[32768];   // 64 KB: 4 wave-private 16KB regions; reused as y tile
  __shared__ float part2[128][2][2];
  __shared__ float pool_sh[4][64];
  __shared__ float2 rs_sh[128];
  int t = threadIdx.x;
  int w = t >> 6, lane = t & 63;
  int wm = w >> 1, wn = w & 1;

  // XCD-chunked bijective swizzle: 6144 = 8 * 768
  int bid = blockIdx.x;
  int swz = ((bid & 7) * 768) + (bid >> 3);
  int rowT = swz / 12, cT = swz % 12;
  int rowBase = rowT << 7;

  // per-block LN-stat reduce (layer 1): hidden under the staging prologue
  if constexpr (LNF) {
    if (t < 128) {
      float s = 0.f, s2 = 0.f;
#pragma unroll
      for (int i = 0; i < 6; ++i) {
        float2 p = rowpart[(size_t)i * (BB * LKN) + rowBase + t];
        s += p.x; s2 += p.y;
      }
      float mm = s * (1.f / EN);
      float var = s2 * (1.f / EN) - mm * mm;
      float rstd = rsqrtf(var + EPSV);
      rs_sh[t] = make_float2(rstd, -mm * rstd);
    }
  }

  // wave-private staging: wave covers A rows wm*64.. and B cols wn*64..
  int koff = (((lane & 3) ^ ((lane >> 3) & 3)) << 3);
  const u16* gA = A + (size_t)(rowBase + wm * 64 + (lane >> 2)) * K + koff;
  const u16* gB = BT + (size_t)((cT << 7) + wn * 64 + (lane >> 2)) * K + koff;

  int lrow = lane & 15, kq = lane >> 4;
  int sOff = ((kq ^ ((lrow >> 1) & 3)) << 3);  // swizzled k-slot for frag reads
  f32x4 acc[4][4] = {};

  u16* myr = SM + (w << 13);   // 8192 u16: A0 | B0 | A1 | B1 (2048 u16 each)

#define PROJ_STAGE(BUFOFS, k0) \
    { _Pragma("unroll") \
      for (int g = 0; g < 4; ++g) { \
        gld16(gA + (size_t)(g * 16) * K + (k0), myr + (BUFOFS) + g * 512); \
        gld16(gB + (size_t)(g * 16) * K + (k0), myr + (BUFOFS) + 2048 + g * 512); } }

#define PROJ_STEP(BUFOFS) \
    { short8 af[4], bf[4]; \
      _Pragma("unroll") \
      for (int m = 0; m < 4; ++m) \
        af[m] = *(const short8*)&myr[(BUFOFS) + ((m * 16 + lrow) << 5) + sOff]; \
      _Pragma("unroll") \
      for (int n = 0; n < 4; ++n) \
        bf[n] = *(const short8*)&myr[(BUFOFS) + 2048 + ((n * 16 + lrow) << 5) + sOff]; \
      _Pragma("unroll") \
      for (int m = 0; m < 4; ++m) \
        _Pragma("unroll") \
        for (int n = 0; n < 4; ++n) \
          acc[m][n] = __builtin_amdgcn_mfma_f32_16x16x32_bf16(af[m], bf[n], acc[m][n], 0, 0, 0); }

  PROJ_STAGE(0, 0)
#pragma unroll 1
  for (int p = 0; p < 12; ++p) {
    PROJ_STAGE(4096, (2 * p + 1) << 5)
    asm volatile("s_waitcnt vmcnt(8)" ::: "memory");
    PROJ_STEP(0)
    if (p < 11) {
      PROJ_STAGE(0, (2 * p + 2) << 5)
      asm volatile("s_waitcnt vmcnt(8)" ::: "memory");
    } else {
      asm volatile("s_waitcnt vmcnt(0)" ::: "memory");
    }
    PROJ_STEP(4096)
  }
#undef PROJ_STAGE
#undef PROJ_STEP

  __syncthreads();   // all waves done with private buffers before SM y-tile reuse

  const int which = cT >= 6;
  const int ecol = ((which ? cT - 6 : cT) << 7);
  const float* bias = which ? bias_v : bias_k;
  const int bidx = rowBase >> 10;

  // ---- E1: y = tanh(pre) -> SM raw (swizzled). No stats here.
  if constexpr (LNF) {
    float un[4], vbn[4];
#pragma unroll
    for (int n = 0; n < 4; ++n) {
      int cc = (cT << 7) + wn * 64 + n * 16 + lrow;
      un[n] = uvec[cc]; vbn[n] = vbvec[cc];
    }
#pragma unroll
    for (int m = 0; m < 4; ++m)
#pragma unroll
      for (int j = 0; j < 4; ++j) {
        int row = wm * 64 + m * 16 + kq * 4 + j;
        float2 st = rs_sh[row];
#pragma unroll
        for (int n = 0; n < 4; ++n) {
          float y = ftanh(st.x * acc[m][n][j] + st.y * un[n] + vbn[n]);
          int c = wn * 64 + n * 16 + lrow;
          int sl = c >> 3;
          int so = ((sl & 7) ^ (row & 7)) | (sl & 8);
          SM[row * 128 + (so << 3) + (c & 7)] = f2bf(y);
        }
      }
  } else {
    float biasv[4];
#pragma unroll
    for (int n = 0; n < 4; ++n)
      biasv[n] = bias[ecol + wn * 64 + n * 16 + lrow];
#pragma unroll
    for (int m = 0; m < 4; ++m)
#pragma unroll
      for (int j = 0; j < 4; ++j) {
        int row = wm * 64 + m * 16 + kq * 4 + j;
#pragma unroll
        for (int n = 0; n < 4; ++n) {
          float y = ftanh(acc[m][n][j] + biasv[n]);
          int c = wn * 64 + n * 16 + lrow;
          int sl = c >> 3;
          int so = ((sl & 7) ^ (row & 7)) | (sl & 8);
          SM[row * 128 + (so << 3) + (c & 7)] = f2bf(y);
        }
      }
  }
  __syncthreads();

  // ---- E2: stats + normalize from SM. thread -> (row = t>>1, col-half = t&1)
  {
    int row = t >> 1, ch = t & 1;
    short8 yv8[8];
    float s = 0.f, s2 = 0.f;
#pragma unroll
    for (int s8 = 0; s8 < 8; ++s8) {
      int sl = (ch << 3) + s8;
      int so = ((sl & 7) ^ (row & 7)) | (sl & 8);
      yv8[s8] = *(const short8*)&SM[row * 128 + (so << 3)];
#pragma unroll
      for (int i = 0; i < 8; ++i) {
        float y = bf2f((u16)yv8[s8][i]);
        s += y; s2 += y * y;
      }
    }
    part2[row][ch][0] = s; part2[row][ch][1] = s2;
    __syncthreads();
    float ssum = part2[row][0][0] + part2[row][1][0];
    float q2 = part2[row][0][1] + part2[row][1][1];
    float mean = ssum * (1.f / 128.f);
    float var = q2 * (1.f / 128.f) - mean * mean;
    float rstd = rsqrtf(var + EPSV);
    const float* gp = which ? g_v : g_k;
    const float* bbp = which ? bb_v : bb_k;
    size_t R = (size_t)rowBase + row;
#pragma unroll
    for (int s8 = 0; s8 < 8; ++s8) {
      int sl = (ch << 3) + s8;
      int so = ((sl & 7) ^ (row & 7)) | (sl & 8);
      int e0 = ecol + (sl << 3);
      float4 g0 = *(const float4*)&gp[e0];
      float4 g1 = *(const float4*)&gp[e0 + 4];
      float4 b0 = *(const float4*)&bbp[e0];
      float4 b1 = *(const float4*)&bbp[e0 + 4];
      float gg[8] = {g0.x, g0.y, g0.z, g0.w, g1.x, g1.y, g1.z, g1.w};
      float bv8[8] = {b0.x, b0.y, b0.z, b0.w, b1.x, b1.y, b1.z, b1.w};
      float ov[8];
#pragma unroll
      for (int i = 0; i < 8; ++i)
        ov[i] = (bf2f((u16)yv8[s8][i]) - mean) * rstd * gg[i] + bv8[i];
      if (!which) {
        float4 q0 = *(const float4*)&qp[(size_t)bidx * EN + e0];
        float4 q1 = *(const float4*)&qp[(size_t)bidx * EN + e0 + 4];
        float qq[8] = {q0.x, q0.y, q0.z, q0.w, q1.x, q1.y, q1.z, q1.w};
#pragma unroll
        for (int i = 0; i < 8; ++i) ov[i] *= qq[i];
      }
      short8 o8;
#pragma unroll
      for (int i = 0; i < 8; ++i) o8[i] = (short)f2bf(ov[i]);
      if (which) *(short8*)&out_v[R * EN + e0] = o8;
      else       *(short8*)&SM[row * 128 + (so << 3)] = o8;
    }
  }
  if (which) return;
  __syncthreads();

  // ---- E3: fused basic GEMM: basic = relu(T[128 l x 128 d] @ Wab[64 c x 128 d]^T + bab)
  const int h = cT;
  const int lt = (rowBase >> 7) & 7;
  f32x4 acc2[2][4] = {};
#pragma unroll
  for (int ks = 0; ks < 4; ++ks) {
    short8 af2[2], bf2[4];
#pragma unroll
    for (int mm = 0; mm < 2; ++mm) {
      int l = w * 32 + mm * 16 + lrow;
      int sl = ks * 4 + kq;
      int so = ((sl & 7) ^ (l & 7)) | (sl & 8);
      af2[mm] = *(const short8*)&SM[l * 128 + so * 8];
    }
#pragma unroll
    for (int n = 0; n < 4; ++n)
      bf2[n] = *(const short8*)&Wab_g[(size_t)(n * 16 + lrow) * 128 + ks * 32 + kq * 8];
#pragma unroll
    for (int mm = 0; mm < 2; ++mm)
#pragma unroll
      for (int n = 0; n < 4; ++n)
        acc2[mm][n] = __builtin_amdgcn_mfma_f32_16x16x32_bf16(af2[mm], bf2[n], acc2[mm][n], 0, 0, 0);
  }

  float wv[4], bv[4];
#pragma unroll
  for (int n = 0; n < 4; ++n) { int c = n * 16 + lrow; wv[n] = Wal_g[c]; bv[n] = bab_g[c]; }
  float kmv[2][4];
  const float* km = kmask + (size_t)bidx * LKN + lt * 128;
#pragma unroll
  for (int mm = 0; mm < 2; ++mm)
#pragma unroll
    for (int j = 0; j < 4; ++j) kmv[mm][j] = km[w * 32 + mm * 16 + kq * 4 + j];
  float balv = bal_g[0];
  float pp[4] = {0.f, 0.f, 0.f, 0.f};
#pragma unroll
  for (int mm = 0; mm < 2; ++mm)
#pragma unroll
    for (int j = 0; j < 4; ++j) {
      float sp = 0.f;
#pragma unroll
      for (int n = 0; n < 4; ++n) {
        float bsv = fmaxf(acc2[mm][n][j] + bv[n], 0.f);
        sp += bsv * wv[n];
        pp[n] += bsv * kmv[mm][j];
      }
      sp += __shfl_xor(sp, 1, 64);
      sp += __shfl_xor(sp, 2, 64);
      sp += __shfl_xor(sp, 4, 64);
      sp += __shfl_xor(sp, 8, 64);
      if (lrow == 0)
        s_out[(((size_t)bidx * HN + h) << 10) + lt * 128 + w * 32 + mm * 16 + kq * 4 + j] = sp + balv;
    }
#pragma unroll
  for (int n = 0; n < 4; ++n) {
    pp[n] += __shfl_xor(pp[n], 16, 64);
    pp[n] += __shfl_xor(pp[n], 32, 64);
  }
  if (lane < 16) {
#pragma unroll
    for (int n = 0; n < 4; ++n) pool_sh[w][n * 16 + lane] = pp[n];
  }
  __syncthreads();
  if (t < 64) {
    float p = pool_sh[0][t] + pool_sh[1][t] + pool_sh[2][t] + pool_sh[3][t];
    pool_part[((((size_t)bidx * HN + h) << 3) + lt) * 64 + t] = p;
  }
}

// Bilinear k-update GEMM (barrier-free K-loop, wave-private staging):
// z = relu(A @ WbiT + qpart[b]) + kf -> bf16 (zbuf) + LN partial sums.
__global__ __launch_bounds__(256, 2) void gemm_bilin(
    const u16* __restrict__ A, const u16* __restrict__ BT,
    const float* __restrict__ biasB, const u16* __restrict__ resid,
    u16* __restrict__ out, float2* __restrict__ rowpart) {
  const int K = EN;
  __shared__ __align__(16) u16 SM[32768];   // 64 KB wave-private regions; reused as y tile
  __shared__ float bps[128], bpq[128];
  int t = threadIdx.x;
  int w = t >> 6, lane = t & 63;
  int wm = w >> 1, wn = w & 1;

  int bid = blockIdx.x;                 // 3072 = 8 * 384
  int swz = ((bid & 7) * 384) + (bid >> 3);
  int rowT = swz / 6, cT = swz % 6;
  int rowBase = rowT << 7;
  int colBase = cT << 7;

  int koff = (((lane & 3) ^ ((lane >> 3) & 3)) << 3);
  const u16* gA = A + (size_t)(rowBase + wm * 64 + (lane >> 2)) * K + koff;
  const u16* gB = BT + (size_t)(colBase + wn * 64 + (lane >> 2)) * K + koff;

  int lrow = lane & 15, kq = lane >> 4;
  int sOff = ((kq ^ ((lrow >> 1) & 3)) << 3);
  f32x4 acc[4][4] = {};

  u16* myr = SM + (w << 13);

#define BIL_STAGE(BUFOFS, k0) \
    { _Pragma("unroll") \
      for (int g = 0; g < 4; ++g) { \
        gld16(gA + (size_t)(g * 16) * K + (k0), myr + (BUFOFS) + g * 512); \
        gld16(gB + (size_t)(g * 16) * K + (k0), myr + (BUFOFS) + 2048 + g * 512); } }

#define BIL_STEP(BUFOFS) \
    { short8 af[4], bf[4]; \
      _Pragma("unroll") \
      for (int m = 0; m < 4; ++m) \
        af[m] = *(const short8*)&myr[(BUFOFS) + ((m * 16 + lrow) << 5) + sOff]; \
      _Pragma("unroll") \
      for (int n = 0; n < 4; ++n) \
        bf[n] = *(const short8*)&myr[(BUFOFS) + 2048 + ((n * 16 + lrow) << 5) + sOff]; \
      _Pragma("unroll") \
      for (int m = 0; m < 4; ++m) \
        _Pragma("unroll") \
        for (int n = 0; n < 4; ++n) \
          acc[m][n] = __builtin_amdgcn_mfma_f32_16x16x32_bf16(af[m], bf[n], acc[m][n], 0, 0, 0); }

  BIL_STAGE(0, 0)
#pragma unroll 1
  for (int p = 0; p < 12; ++p) {
    BIL_STAGE(4096, (2 * p + 1) << 5)
    asm volatile("s_waitcnt vmcnt(8)" ::: "memory");
    BIL_STEP(0)
    if (p < 11) {
      BIL_STAGE(0, (2 * p + 2) << 5)
      asm volatile("s_waitcnt vmcnt(8)" ::: "memory");
    } else {
      asm volatile("s_waitcnt vmcnt(0)" ::: "memory");
    }
    BIL_STEP(4096)
  }
#undef BIL_STAGE
#undef BIL_STEP

  __syncthreads();   // waves done with private buffers

  const int bidx = rowBase >> 10;
  // E1: y = relu(acc + qpart) -> SM swizzled bf16 (acc dies)
  {
    float qv[4];
#pragma unroll
    for (int n = 0; n < 4; ++n)
      qv[n] = biasB[(size_t)bidx * EN + colBase + wn * 64 + n * 16 + lrow];
#pragma unroll
    for (int m = 0; m < 4; ++m)
#pragma unroll
      for (int j = 0; j < 4; ++j) {
        int row = wm * 64 + m * 16 + kq * 4 + j;
#pragma unroll
        for (int n = 0; n < 4; ++n) {
          float y = fmaxf(acc[m][n][j] + qv[n], 0.f);
          int c = wn * 64 + n * 16 + lrow;
          int sl = c >> 3;
          int so = ((sl & 7) ^ (row & 7)) | (sl & 8);
          SM[row * 128 + (so << 3) + (c & 7)] = f2bf(y);
        }
      }
  }
  __syncthreads();

  // E2: remap (row = t>>1, half = t&1); coalesced resid read + out write;
  // accumulate LN partials of the final bf16 z values.
  {
    int row = t >> 1, ch = t & 1;
    size_t R = (size_t)rowBase + row;
    float s = 0.f, s2 = 0.f;
#pragma unroll
    for (int s8 = 0; s8 < 8; ++s8) {
      int sl = (ch << 3) + s8;
      int so = ((sl & 7) ^ (row & 7)) | (sl & 8);
      short8 yv = *(const short8*)&SM[row * 128 + (so << 3)];
      int e0 = colBase + (sl << 3);
      short8 rv = *(const short8*)&resid[R * EN + e0];
      short8 o8;
#pragma unroll
      for (int i = 0; i < 8; ++i) {
        u16 zb = f2bf(bf2f((u16)yv[i]) + bf2f((u16)rv[i]));
        o8[i] = (short)zb;
        float zf = bf2f(zb);
        s += zf; s2 += zf * zf;
      }
      *(short8*)&out[R * EN + e0] = o8;
    }
    if (ch == 1) { bps[row] = s; bpq[row] = s2; }
    __syncthreads();
    if (ch == 0)
      rowpart[(size_t)cT * (BB * LKN) + R] = make_float2(s + bps[row], s2 + bpq[row]);
  }
}

// Fused attention finish per (b,h): softmax(s) in LDS, pool->a_c, v2a, q out.
__global__ __launch_bounds__(256) void attn_fin(
    const float* __restrict__ s_in, const float* __restrict__ kmask,
    const float* __restrict__ msum, const float* __restrict__ pool_part,
    const float* __restrict__ Wac, const float* __restrict__ bac,
    const u16* __restrict__ v2, const float* __restrict__ v1,
    float* __restrict__ q_cur, float* __restrict__ feats, int slot) {
  __shared__ float as_sh[LKN];
  __shared__ float red[256];
  __shared__ float red8[16][129];
  __shared__ float pool_sh[64];
  __shared__ float ac_sh[128];
  int t = threadIdx.x;
  int h = blockIdx.x, b = blockIdx.y;
  const float* sb = s_in + (((size_t)b * HN + h) << 10);
  const float* km = kmask + (size_t)b * LKN;
  float v[4];
  float mx = -1e30f;
#pragma unroll
  for (int j = 0; j < 4; ++j) {
    int l = t * 4 + j;
    float x = sb[l];
    if (km[l] == 0.f) x = -1e9f;
    v[j] = x; mx = fmaxf(mx, x);
  }
  red[t] = mx; __syncthreads();
  for (int o = 128; o > 0; o >>= 1) { if (t < o) red[t] = fmaxf(red[t], red[t + o]); __syncthreads(); }
  float mxv = red[0];
  __syncthreads();
  float sum = 0.f;
#pragma unroll
  for (int j = 0; j < 4; ++j) { v[j] = __expf(v[j] - mxv); sum += v[j]; }
  red[t] = sum; __syncthreads();
  for (int o = 128; o > 0; o >>= 1) { if (t < o) red[t] += red[t + o]; __syncthreads(); }
  float inv = 1.f / red[0];
#pragma unroll
  for (int j = 0; j < 4; ++j) as_sh[t * 4 + j] = v[j] * inv;
  if (t < 64) {
    float p = 0.f;
    for (int lt = 0; lt < 8; ++lt)
      p += pool_part[((((size_t)b * HN + h) << 3) + lt) * 64 + t];
    pool_sh[t] = p / msum[b];
  }
  __syncthreads();
  if (t < 128) {
    float a = 0.f;
    for (int j = 0; j < 64; ++j) a += pool_sh[j] * Wac[j * HDN + t];
    ac_sh[t] = 1.f / (1.f + __expf(-(a + bac[t])));
  }
  __syncthreads();
  // v2a: 16 d-octs x 16 l-slices, short8 (16B) loads
  {
    int o = t & 15, sl = t >> 4;
    const u16* vb = v2 + ((size_t)b * LKN) * EN + h * HDN + o * 8;
    float a8[8] = {};
    for (int l = sl; l < LKN; l += 16) {
      short8 u = *(const short8*)&vb[(size_t)l * EN];
      float wgt = as_sh[l];
#pragma unroll
      for (int i = 0; i < 8; ++i) a8[i] += wgt * bf2f((u16)u[i]);
    }
#pragma unroll
    for (int i = 0; i < 8; ++i) red8[sl][o * 8 + i] = a8[i];
  }
  __syncthreads();
  if (t < 128) {
    float va = 0.f;
#pragma unroll
    for (int s = 0; s < 16; ++s) va += red8[s][t];
    size_t idx = (size_t)b * EN + h * HDN + t;
    float q = v1[idx] * va * ac_sh[t];
    q_cur[idx] = q;
    feats[(size_t)b * 3 * EN + slot * EN + h * HDN + t] = q;
  }
}

// final: out = ln(feats(B x 2304) @ Wp + bp)
__global__ __launch_bounds__(768) void final_kernel(
    const float* __restrict__ feats, const float* __restrict__ Wp,
    const float* __restrict__ bp, const float* __restrict__ g,
    const float* __restrict__ bb, float* __restrict__ outp) {
  __shared__ float fs[2304];
  __shared__ float red[24];
  __shared__ float mv[2];
  int t = threadIdx.x, b = blockIdx.x;
  fs[t] = feats[(size_t)b * 2304 + t];
  fs[t + 768] = feats[(size_t)b * 2304 + 768 + t];
  fs[t + 1536] = feats[(size_t)b * 2304 + 1536 + t];
  __syncthreads();
  float acc = 0.f;
  for (int k = 0; k < 2304; ++k) acc += fs[k] * Wp[(size_t)k * EN + t];
  float y = acc + bp[t];
  float s = y, s2 = y * y;
  for (int o = 32; o > 0; o >>= 1) { s += __shfl_down(s, o, 64); s2 += __shfl_down(s2, o, 64); }
  int wid = t >> 6, lane = t & 63;
  if (lane == 0) { red[wid] = s; red[12 + wid] = s2; }
  __syncthreads();
  if (t == 0) {
    float ts = 0.f, ts2 = 0.f;
    for (int i = 0; i < 12; ++i) { ts += red[i]; ts2 += red[12 + i]; }
    float m = ts * (1.f / EN), var = ts2 * (1.f / EN) - m * m;
    mv[0] = m; mv[1] = rsqrtf(var + EPSV);
  }
  __syncthreads();
  outp[(size_t)b * EN + t] = (y - mv[0]) * mv[1] * g[t] + bb[t];
}

// ---------------------------------------------------------------------------
extern "C" void kernel_launch(void* const* d_in, const int* in_sizes, int n_in,
                              void* d_out, int out_size, void* d_ws, size_t ws_size,
                              hipStream_t stream) {
  const float* q_feat = (const float*)d_in[0];
  const float* k_feats = (const float*)d_in[1];
  const float* q_mask = (const float*)d_in[2];
  const float* k_mask = (const float*)d_in[3];
  const float* Wq = (const float*)d_in[4];
  const float* bq = (const float*)d_in[5];
  const float* gq_g = (const float*)d_in[6];
  const float* gq_b = (const float*)d_in[7];
  const float* Wk = (const float*)d_in[8];
  const float* bk = (const float*)d_in[9];
  const float* gk_g = (const float*)d_in[10];
  const float* gk_b = (const float*)d_in[11];
  const float* Wv1 = (const float*)d_in[12];
  const float* bv1 = (const float*)d_in[13];
  const float* g1_g = (const float*)d_in[14];
  const float* g1_b = (const float*)d_in[15];
  const float* Wv2 = (const float*)d_in[16];
  const float* bv2 = (const float*)d_in[17];
  const float* g2_g = (const float*)d_in[18];
  const float* g2_b = (const float*)d_in[19];
  const float* Wab = (const float*)d_in[20];
  const float* bab = (const float*)d_in[21];
  const float* Wal = (const float*)d_in[22];
  const float* bal = (const float*)d_in[23];
  const float* Wac = (const float*)d_in[24];
  const float* bac = (const float*)d_in[25];
  const float* Wbi = (const float*)d_in[26];
  const float* bbi = (const float*)d_in[27];
  const float* lnb_g = (const float*)d_in[28];
  const float* lnb_b = (const float*)d_in[29];
  const float* Wp = (const float*)d_in[30];
  const float* bp = (const float*)d_in[31];
  const float* ln_g = (const float*)d_in[32];
  const float* ln_b = (const float*)d_in[33];
  float* out = (float*)d_out;
  (void)in_sizes; (void)n_in; (void)out_size; (void)ws_size;

  char* ws = (char*)d_ws;
  size_t off = 0;
  auto alloc = [&](size_t bytes) -> char* {
    char* p = ws + off;
    off += (bytes + 255) & ~(size_t)255;
    return p;
  };
  const size_t MK = (size_t)BB * LKN;  // 65536
  u16* kf = (u16*)alloc(MK * EN * 2);
  u16* zbuf = (u16*)alloc(MK * EN * 2);  // bilin z scratch (pre-LN)
  u16* v2b = (u16*)alloc(MK * EN * 2);
  u16* WkvT = (u16*)alloc((size_t)2 * 1536 * EN * 2);  // per layer: [Wk^T; Wv2^T] (L1: g folded)
  u16* WbiT = (u16*)alloc((size_t)EN * EN * 2);
  u16* WabT = (u16*)alloc((size_t)2 * D2N * HDN * 2);
  float* feats = (float*)alloc((size_t)BB * 3 * EN * 4);
  float* q_cur = (float*)alloc((size_t)BB * EN * 4);
  float* qp = (float*)alloc((size_t)BB * EN * 4);
  float* v1 = (float*)alloc((size_t)BB * EN * 4);
  float* qpart = (float*)alloc((size_t)BB * EN * 4);
  float* sbuf = (float*)alloc((size_t)BB * HN * LKN * 4);
  float* poolp = (float*)alloc((size_t)BB * HN * 8 * D2N * 4);
  float* msum = (float*)alloc((size_t)BB * 4);
  float2* rowpart = (float2*)alloc((size_t)6 * MK * 8);
  float* uvec = (float*)alloc(1536 * 4);
  float* vbvec = (float*)alloc(1536 * 4);

  // ---- fused prep (conv + 5x transpose + Wab transpose + uv + poolq + msum)
  prep_kernel<<<NB_PREP, 256, 0, stream>>>(
      k_feats, kf, Wk, Wv2, Wbi, lnb_g, WkvT, WbiT, Wab, WabT,
      lnb_b, bk + EN, bv2 + EN, uvec, vbvec,
      q_feat, q_mask, q_cur, feats, k_mask, msum);

  // ---- layer 0
  qside2_kernel<<<dim3(BB, 2), 768, 0, stream>>>(
      q_cur, Wq, bq, gq_g, gq_b, qp,
      Wv1, bv1, g1_g, g1_b, v1, nullptr, nullptr, nullptr);
  gemm_proj<false><<<6144, 256, 0, stream>>>(
      kf, WkvT, bk, gk_g, gk_b, qp,
      bv2, g2_g, g2_b, v2b,
      WabT, bab, Wal, bal, k_mask, sbuf, poolp,
      nullptr, nullptr, nullptr);
  attn_fin<<<dim3(HN, BB), 256, 0, stream>>>(
      sbuf, k_mask, msum, poolp, Wac, bac, v2b, v1, q_cur, feats, 1);

  // ---- layer 1: bilin -> (z, LN partials); proj consumes z with LN applied
  //      algebraically (g folded into W, u/vb correction, per-block rowstat).
  qside2_kernel<<<dim3(BB, 3), 768, 0, stream>>>(
      q_cur, Wq + (size_t)EN * EN, bq + EN, gq_g + EN, gq_b + EN, qp,
      Wv1 + (size_t)EN * EN, bv1 + EN, g1_g + EN, g1_b + EN, v1,
      Wbi, bbi, qpart);
  gemm_bilin<<<3072, 256, 0, stream>>>(kf, WbiT, qpart, kf, zbuf, rowpart);
  gemm_proj<true><<<6144, 256, 0, stream>>>(
      zbuf, WkvT + (size_t)1536 * EN, bk + EN, gk_g + EN, gk_b + EN, qp,
      bv2 + EN, g2_g + EN, g2_b + EN, v2b,
      WabT + (size_t)D2N * HDN, bab + D2N, Wal + D2N, bal + 1, k_mask, sbuf, poolp,
      rowpart, uvec, vbvec);
  attn_fin<<<dim3(HN, BB), 256, 0, stream>>>(
      sbuf, k_mask, msum, poolp, Wac + (size_t)D2N * HDN, bac + HDN, v2b, v1, q_cur, feats, 2);

  final_kernel<<<BB, EN, 0, stream>>>(feats, Wp, bp, ln_g, ln_b, out);
}

// Round 18
// 933.960 us; speedup vs baseline: 1.2640x; 1.2640x over previous
//
#include <hip/hip_runtime.h>
#include <math.h>

#define DEVI static __device__ __forceinline__

typedef unsigned short u16;
typedef __attribute__((ext_vector_type(8))) short short8;
typedef __attribute__((ext_vector_type(4))) float f32x4;

DEVI float bf2f(u16 u) { union { float f; unsigned int i; } c; c.i = ((unsigned int)u) << 16; return c.f; }
DEVI u16 f2bf(float f) {
  union { float f; unsigned int i; } c; c.f = f;
  unsigned int r = c.i + 0x7FFFu + ((c.i >> 16) & 1u);
  return (u16)(r >> 16);
}

DEVI float ftanh(float x) {
  float e = __expf(2.f * x);
  return 1.f - 2.f * __builtin_amdgcn_rcpf(e + 1.f);
}

// async global->LDS, 16B per lane. LDS base must be wave-uniform; HW adds lane*16B.
DEVI void gld16(const u16* g, u16* l) {
  __builtin_amdgcn_global_load_lds((const __attribute__((address_space(1))) unsigned int*)g,
                                   (__attribute__((address_space(3))) unsigned int*)l, 16, 0, 0);
}

#define BB 64
#define LQN 128
#define LKN 1024
#define EN 768
#define HN 6
#define HDN 128
#define D2N 64
#define EPSV 1e-5f

// prep role block counts
#define NB_CONV 3072
#define NB_TW5 2880
#define NB_WAB 16
#define NB_UV 96
#define NB_PQ 64
#define NB_MS 64
#define NB_PREP (NB_CONV + NB_TW5 + NB_WAB + NB_UV + NB_PQ + NB_MS)

// ---------------------------------------------------------------------------
// Fused prep: conv(k_feats->kf bf16) | transpose 5x768^2 (L1 g-fold) |
// transpose Wab | uv vectors | poolq | msum.  All roles independent.
__global__ __launch_bounds__(256) void prep_kernel(
    const float* __restrict__ k_feats, u16* __restrict__ kf,
    const float* __restrict__ Wk, const float* __restrict__ Wv2,
    const float* __restrict__ Wbi, const float* __restrict__ lnb_g,
    u16* __restrict__ WkvT, u16* __restrict__ WbiT,
    const float* __restrict__ Wab, u16* __restrict__ WabT,
    const float* __restrict__ lnb_b, const float* __restrict__ bkL1,
    const float* __restrict__ bv2L1, float* __restrict__ uvec,
    float* __restrict__ vbvec,
    const float* __restrict__ qf, const float* __restrict__ qm,
    float* __restrict__ q_cur, float* __restrict__ feats,
    const float* __restrict__ km, float* __restrict__ msum) {
  __shared__ float ls[1056];   // union scratch: transpose tile / uv partials / msum red
  int b = blockIdx.x, t = threadIdx.x;

  if (b < NB_CONV) {  // fp32 -> bf16, grid-strided, short8 stores
    size_t n8 = (size_t)BB * LKN * EN / 8;
    for (size_t i = (size_t)b * 256 + t; i < n8; i += (size_t)NB_CONV * 256) {
      float4 a = ((const float4*)k_feats)[2 * i];
      float4 c = ((const float4*)k_feats)[2 * i + 1];
      short8 o;
      o[0] = (short)f2bf(a.x); o[1] = (short)f2bf(a.y); o[2] = (short)f2bf(a.z); o[3] = (short)f2bf(a.w);
      o[4] = (short)f2bf(c.x); o[5] = (short)f2bf(c.y); o[6] = (short)f2bf(c.z); o[7] = (short)f2bf(c.w);
      *(short8*)&kf[i * 8] = o;
    }
    return;
  }
  b -= NB_CONV;
  if (b < NB_TW5) {  // transpose+cvt 768x768: z = which matrix
    int z = b / 576, rem = b % 576;
    int kb = (rem / 24) * 32, nb = (rem % 24) * 32;
    const float* src;
    u16* dst;
    bool fold = (z == 1) || (z == 3);
    if (z < 2) { src = Wk + (size_t)z * EN * EN; dst = WkvT + (size_t)z * 1536 * EN; }
    else if (z < 4) { src = Wv2 + (size_t)(z - 2) * EN * EN; dst = WkvT + (size_t)(z - 2) * 1536 * EN + (size_t)EN * EN; }
    else { src = Wbi + (size_t)EN * EN; dst = WbiT; }
    int tx = t & 31, ty = t >> 5;  // 32 x 8
    for (int j = 0; j < 32; j += 8) {
      float v = src[(size_t)(kb + ty + j) * EN + nb + tx];
      if (fold) v *= lnb_g[kb + ty + j];
      ls[(ty + j) * 33 + tx] = v;
    }
    __syncthreads();
    for (int j = 0; j < 32; j += 8)
      dst[(size_t)(nb + ty + j) * EN + kb + tx] = f2bf(ls[tx * 33 + ty + j]);
    return;
  }
  b -= NB_TW5;
  if (b < NB_WAB) {  // transpose+cvt Wab (HD x D2) -> WabT (D2 x HD), 2 layers
    int z = b / 8, rem = b % 8;
    int kb = (rem / 2) * 32, nb = (rem % 2) * 32;
    const float* src = Wab + (size_t)z * HDN * D2N;
    u16* dst = WabT + (size_t)z * D2N * HDN;
    int tx = t & 31, ty = t >> 5;
    for (int j = 0; j < 32; j += 8)
      ls[(ty + j) * 33 + tx] = src[(size_t)(kb + ty + j) * D2N + nb + tx];
    __syncthreads();
    for (int j = 0; j < 32; j += 8)
      dst[(size_t)(nb + ty + j) * HDN + kb + tx] = f2bf(ls[tx * 33 + ty + j]);
    return;
  }
  b -= NB_WAB;
  if (b < NB_UV) {  // u = g@W, vb = bb@W + bias for layer-1 Wk/Wv2
    float* pu = ls;            // [16][17]
    float* pv = ls + 272;      // [16][17]
    int col = t & 15, ks = t >> 4;
    int c = b * 16 + col;
    int part = c >= EN;
    int cc = part ? c - EN : c;  // EN is NOT a power of two - no mask tricks
    const float* W = (part ? Wv2 : Wk) + (size_t)EN * EN;  // layer-1 weights
    float u = 0.f, vb = 0.f;
    for (int k = ks * 48; k < ks * 48 + 48; ++k) {
      float w = W[(size_t)k * EN + cc];
      u += lnb_g[k] * w;
      vb += lnb_b[k] * w;
    }
    pu[ks * 17 + col] = u; pv[ks * 17 + col] = vb;
    __syncthreads();
    if (t < 16) {
      int c2 = b * 16 + t;
      int part2 = c2 >= EN;
      int cc2 = part2 ? c2 - EN : c2;
      float su = 0.f, sv = 0.f;
#pragma unroll
      for (int s = 0; s < 16; ++s) { su += pu[s * 17 + t]; sv += pv[s * 17 + t]; }
      sv += part2 ? bv2L1[cc2] : bkL1[cc2];
      uvec[c2] = su;
      vbvec[c2] = sv;
    }
    return;
  }
  b -= NB_UV;
  if (b < NB_PQ) {  // mean-pool q_feat -> q_cur + feats slot 0 (3 cols/thread)
    float s0 = 0.f, s1 = 0.f, s2 = 0.f, ms = 0.f;
    for (int l = 0; l < LQN; ++l) {
      float w = qm[b * LQN + l];
      const float* row = qf + ((size_t)b * LQN + l) * EN;
      s0 += row[t] * w; s1 += row[t + 256] * w; s2 += row[t + 512] * w;
      ms += w;
    }
    float inv = 1.f / ms;
    q_cur[(size_t)b * EN + t] = s0 * inv;
    q_cur[(size_t)b * EN + t + 256] = s1 * inv;
    q_cur[(size_t)b * EN + t + 512] = s2 * inv;
    feats[(size_t)b * 3 * EN + t] = s0 * inv;
    feats[(size_t)b * 3 * EN + t + 256] = s1 * inv;
    feats[(size_t)b * 3 * EN + t + 512] = s2 * inv;
    return;
  }
  b -= NB_PQ;
  {  // msum
    float s = 0.f;
    for (int l = t; l < LKN; l += 256) s += km[b * LKN + l];
    ls[t] = s; __syncthreads();
    for (int o = 128; o > 0; o >>= 1) { if (t < o) ls[t] += ls[t + o]; __syncthreads(); }
    if (t == 0) msum[b] = ls[0];
  }
}

// merged q-side projections: y-grid picks {Wq->qp}, {Wv1->v1}, or {Wbi->qpart}
__global__ __launch_bounds__(768) void qside2_kernel(
    const float* __restrict__ q_in,
    const float* __restrict__ W0, const float* __restrict__ b0,
    const float* __restrict__ g0, const float* __restrict__ bb0, float* __restrict__ o0,
    const float* __restrict__ W1, const float* __restrict__ b1,
    const float* __restrict__ g1, const float* __restrict__ bb1, float* __restrict__ o1,
    const float* __restrict__ W2, const float* __restrict__ b2, float* __restrict__ o2) {
  __shared__ float qs[EN];
  __shared__ float ys[EN];
  __shared__ float mh[HN], rh[HN];
  int t = threadIdx.x, b = blockIdx.x, which = blockIdx.y;
  const float* W = which == 0 ? W0 : (which == 1 ? W1 : W2);
  const float* bvec = which == 0 ? b0 : (which == 1 ? b1 : b2);
  qs[t] = q_in[(size_t)b * EN + t];
  __syncthreads();
  float acc = 0.f;
  for (int k = 0; k < EN; ++k) acc += qs[k] * W[(size_t)k * EN + t];
  if (which == 2) {  // qpart: no activation / GN
    o2[(size_t)b * EN + t] = acc + bvec[t];
    return;
  }
  const float* g = which ? g1 : g0;
  const float* bb = which ? bb1 : bb0;
  float* outp = which ? o1 : o0;
  float y = tanhf(acc + bvec[t]);
  ys[t] = y; __syncthreads();
  if (t < HN) {
    float s = 0.f, s2 = 0.f;
    for (int d = 0; d < HDN; ++d) { float v = ys[t * HDN + d]; s += v; s2 += v * v; }
    float m = s * (1.f / HDN), var = s2 * (1.f / HDN) - m * m;
    mh[t] = m; rh[t] = rsqrtf(var + EPSV);
  }
  __syncthreads();
  int h = t >> 7;
  outp[(size_t)b * EN + t] = (y - mh[h]) * rh[h] * g[t] + bb[t];
}

// ---------------------------------------------------------------------------
// Merged projection GEMM + fused "basic" attention GEMM.
// LNF=true (layer 1): A is pre-LN z; LN applied algebraically:
//   pre = rstd*acc + m2*u[c] + vb[c]   (W has lnb_g folded in).
// Per-block rowstat computed in-kernel from rowpart partials (no finstat pass).
template <bool LNF>
__global__ __launch_bounds__(256, 4) void gemm_proj(
    const u16* __restrict__ A, const u16* __restrict__ BT,
    const float* __restrict__ bias_k, const float* __restrict__ g_k,
    const float* __restrict__ bb_k, const float* __restrict__ qp,
    const float* __restrict__ bias_v, const float* __restrict__ g_v,
    const float* __restrict__ bb_v, u16* __restrict__ out_v,
    const u16* __restrict__ Wab_g, const float* __restrict__ bab_g,
    const float* __restrict__ Wal_g, const float* __restrict__ bal_g,
    const float* __restrict__ kmask, float* __restrict__ s_out,
    float* __restrict__ pool_part,
    const float2* __restrict__ rowpart, const float* __restrict__ uvec,
    const float* __restrict__ vbvec) {
  const int K = EN;
  __shared__ __align__(16) u16 SM[16384];   // 32 KB: As | Bs, reused as y/kp tile
  __shared__ float part2[128][2][2];
  __shared__ float pool_sh[4][64];
  __shared__ float2 rs_sh[128];
  u16* As = SM;
  u16* Bs = SM + 8192;
  int t = threadIdx.x;
  int w = t >> 6, lane = t & 63;
  int wm = w >> 1, wn = w & 1;

  // XCD-chunked bijective swizzle: 6144 = 8 * 768
  int bid = blockIdx.x;
  int swz = ((bid & 7) * 768) + (bid >> 3);
  int rowT = swz / 12, cT = swz % 12;
  int rowBase = rowT << 7;

  // per-block LN-stat reduce (layer 1): hidden under the staging prologue
  if constexpr (LNF) {
    if (t < 128) {
      float s = 0.f, s2 = 0.f;
#pragma unroll
      for (int i = 0; i < 6; ++i) {
        float2 p = rowpart[(size_t)i * (BB * LKN) + rowBase + t];
        s += p.x; s2 += p.y;
      }
      float mm = s * (1.f / EN);
      float var = s2 * (1.f / EN) - mm * mm;
      float rstd = rsqrtf(var + EPSV);
      rs_sh[t] = make_float2(rstd, -mm * rstd);
    }
  }

  int koff = (((lane & 3) ^ ((lane >> 3) & 3)) << 3);
  const u16* gA = A + (size_t)(rowBase + (w << 5) + (lane >> 2)) * K + koff;
  const u16* gB = BT + (size_t)((cT << 7) + (w << 5) + (lane >> 2)) * K + koff;

  int lrow = lane & 15, kq = lane >> 4;
  int sOff = ((kq ^ ((lrow >> 1) & 3)) << 3);  // swizzled k-slot for frag reads
  f32x4 acc[4][4] = {};

  u16* lA0b = As + (w << 10);
  u16* lB0b = Bs + (w << 10);
  u16* lA1b = As + 4096 + (w << 10);
  u16* lB1b = Bs + 4096 + (w << 10);

#define PROJ_PREF(LA, LB, k0) \
    { gld16(gA + (k0), LA); gld16(gA + (size_t)16 * K + (k0), LA + 512); \
      gld16(gB + (k0), LB); gld16(gB + (size_t)16 * K + (k0), LB + 512); }

#define PROJ_STEP(BASE) \
    { short8 af[4], bf[4]; \
      _Pragma("unroll") \
      for (int m = 0; m < 4; ++m) \
        af[m] = *(const short8*)&As[(BASE) + ((wm * 64 + m * 16 + lrow) << 5) + sOff]; \
      _Pragma("unroll") \
      for (int n = 0; n < 4; ++n) \
        bf[n] = *(const short8*)&Bs[(BASE) + ((wn * 64 + n * 16 + lrow) << 5) + sOff]; \
      _Pragma("unroll") \
      for (int m = 0; m < 4; ++m) \
        _Pragma("unroll") \
        for (int n = 0; n < 4; ++n) \
          acc[m][n] = __builtin_amdgcn_mfma_f32_16x16x32_bf16(af[m], bf[n], acc[m][n], 0, 0, 0); }

  PROJ_PREF(lA0b, lB0b, 0)
#pragma unroll 1
  for (int p = 0; p < 12; ++p) {
    __syncthreads();
    PROJ_PREF(lA1b, lB1b, (2 * p + 1) << 5)
    PROJ_STEP(0)
    __syncthreads();
    if (p < 11) PROJ_PREF(lA0b, lB0b, (2 * p + 2) << 5)
    PROJ_STEP(4096)
  }
#undef PROJ_PREF
#undef PROJ_STEP

  __syncthreads();   // all waves done reading As/Bs before SM is overwritten

  const int which = cT >= 6;
  const int ecol = ((which ? cT - 6 : cT) << 7);
  const float* bias = which ? bias_v : bias_k;
  const int bidx = rowBase >> 10;

  // ---- E1: y = tanh(pre) -> SM raw (swizzled). No stats here.
  if constexpr (LNF) {
    float un[4], vbn[4];
#pragma unroll
    for (int n = 0; n < 4; ++n) {
      int cc = (cT << 7) + wn * 64 + n * 16 + lrow;
      un[n] = uvec[cc]; vbn[n] = vbvec[cc];
    }
#pragma unroll
    for (int m = 0; m < 4; ++m)
#pragma unroll
      for (int j = 0; j < 4; ++j) {
        int row = wm * 64 + m * 16 + kq * 4 + j;
        float2 st = rs_sh[row];
#pragma unroll
        for (int n = 0; n < 4; ++n) {
          float y = ftanh(st.x * acc[m][n][j] + st.y * un[n] + vbn[n]);
          int c = wn * 64 + n * 16 + lrow;
          int sl = c >> 3;
          int so = ((sl & 7) ^ (row & 7)) | (sl & 8);
          SM[row * 128 + (so << 3) + (c & 7)] = f2bf(y);
        }
      }
  } else {
    float biasv[4];
#pragma unroll
    for (int n = 0; n < 4; ++n)
      biasv[n] = bias[ecol + wn * 64 + n * 16 + lrow];
#pragma unroll
    for (int m = 0; m < 4; ++m)
#pragma unroll
      for (int j = 0; j < 4; ++j) {
        int row = wm * 64 + m * 16 + kq * 4 + j;
#pragma unroll
        for (int n = 0; n < 4; ++n) {
          float y = ftanh(acc[m][n][j] + biasv[n]);
          int c = wn * 64 + n * 16 + lrow;
          int sl = c >> 3;
          int so = ((sl & 7) ^ (row & 7)) | (sl & 8);
          SM[row * 128 + (so << 3) + (c & 7)] = f2bf(y);
        }
      }
  }
  __syncthreads();

  // ---- E2: stats + normalize from SM. thread -> (row = t>>1, col-half = t&1)
  {
    int row = t >> 1, ch = t & 1;
    short8 yv8[8];
    float s = 0.f, s2 = 0.f;
#pragma unroll
    for (int s8 = 0; s8 < 8; ++s8) {
      int sl = (ch << 3) + s8;
      int so = ((sl & 7) ^ (row & 7)) | (sl & 8);
      yv8[s8] = *(const short8*)&SM[row * 128 + (so << 3)];
#pragma unroll
      for (int i = 0; i < 8; ++i) {
        float y = bf2f((u16)yv8[s8][i]);
        s += y; s2 += y * y;
      }
    }
    part2[row][ch][0] = s; part2[row][ch][1] = s2;
    __syncthreads();
    float ssum = part2[row][0][0] + part2[row][1][0];
    float q2 = part2[row][0][1] + part2[row][1][1];
    float mean = ssum * (1.f / 128.f);
    float var = q2 * (1.f / 128.f) - mean * mean;
    float rstd = rsqrtf(var + EPSV);
    const float* gp = which ? g_v : g_k;
    const float* bbp = which ? bb_v : bb_k;
    size_t R = (size_t)rowBase + row;
#pragma unroll
    for (int s8 = 0; s8 < 8; ++s8) {
      int sl = (ch << 3) + s8;
      int so = ((sl & 7) ^ (row & 7)) | (sl & 8);
      int e0 = ecol + (sl << 3);
      float4 g0 = *(const float4*)&gp[e0];
      float4 g1 = *(const float4*)&gp[e0 + 4];
      float4 b0 = *(const float4*)&bbp[e0];
      float4 b1 = *(const float4*)&bbp[e0 + 4];
      float gg[8] = {g0.x, g0.y, g0.z, g0.w, g1.x, g1.y, g1.z, g1.w};
      float bv8[8] = {b0.x, b0.y, b0.z, b0.w, b1.x, b1.y, b1.z, b1.w};
      float ov[8];
#pragma unroll
      for (int i = 0; i < 8; ++i)
        ov[i] = (bf2f((u16)yv8[s8][i]) - mean) * rstd * gg[i] + bv8[i];
      if (!which) {
        float4 q0 = *(const float4*)&qp[(size_t)bidx * EN + e0];
        float4 q1 = *(const float4*)&qp[(size_t)bidx * EN + e0 + 4];
        float qq[8] = {q0.x, q0.y, q0.z, q0.w, q1.x, q1.y, q1.z, q1.w};
#pragma unroll
        for (int i = 0; i < 8; ++i) ov[i] *= qq[i];
      }
      short8 o8;
#pragma unroll
      for (int i = 0; i < 8; ++i) o8[i] = (short)f2bf(ov[i]);
      if (which) *(short8*)&out_v[R * EN + e0] = o8;
      else       *(short8*)&SM[row * 128 + (so << 3)] = o8;
    }
  }
  if (which) return;
  __syncthreads();

  // ---- E3: fused basic GEMM: basic = relu(T[128 l x 128 d] @ Wab[64 c x 128 d]^T + bab)
  const int h = cT;
  const int lt = (rowBase >> 7) & 7;
  f32x4 acc2[2][4] = {};
#pragma unroll
  for (int ks = 0; ks < 4; ++ks) {
    short8 af2[2], bf2[4];
#pragma unroll
    for (int mm = 0; mm < 2; ++mm) {
      int l = w * 32 + mm * 16 + lrow;
      int sl = ks * 4 + kq;
      int so = ((sl & 7) ^ (l & 7)) | (sl & 8);
      af2[mm] = *(const short8*)&SM[l * 128 + so * 8];
    }
#pragma unroll
    for (int n = 0; n < 4; ++n)
      bf2[n] = *(const short8*)&Wab_g[(size_t)(n * 16 + lrow) * 128 + ks * 32 + kq * 8];
#pragma unroll
    for (int mm = 0; mm < 2; ++mm)
#pragma unroll
      for (int n = 0; n < 4; ++n)
        acc2[mm][n] = __builtin_amdgcn_mfma_f32_16x16x32_bf16(af2[mm], bf2[n], acc2[mm][n], 0, 0, 0);
  }

  float wv[4], bv[4];
#pragma unroll
  for (int n = 0; n < 4; ++n) { int c = n * 16 + lrow; wv[n] = Wal_g[c]; bv[n] = bab_g[c]; }
  float kmv[2][4];
  const float* km = kmask + (size_t)bidx * LKN + lt * 128;
#pragma unroll
  for (int mm = 0; mm < 2; ++mm)
#pragma unroll
    for (int j = 0; j < 4; ++j) kmv[mm][j] = km[w * 32 + mm * 16 + kq * 4 + j];
  float balv = bal_g[0];
  float pp[4] = {0.f, 0.f, 0.f, 0.f};
#pragma unroll
  for (int mm = 0; mm < 2; ++mm)
#pragma unroll
    for (int j = 0; j < 4; ++j) {
      float sp = 0.f;
#pragma unroll
      for (int n = 0; n < 4; ++n) {
        float bsv = fmaxf(acc2[mm][n][j] + bv[n], 0.f);
        sp += bsv * wv[n];
        pp[n] += bsv * kmv[mm][j];
      }
      sp += __shfl_xor(sp, 1, 64);
      sp += __shfl_xor(sp, 2, 64);
      sp += __shfl_xor(sp, 4, 64);
      sp += __shfl_xor(sp, 8, 64);
      if (lrow == 0)
        s_out[(((size_t)bidx * HN + h) << 10) + lt * 128 + w * 32 + mm * 16 + kq * 4 + j] = sp + balv;
    }
#pragma unroll
  for (int n = 0; n < 4; ++n) {
    pp[n] += __shfl_xor(pp[n], 16, 64);
    pp[n] += __shfl_xor(pp[n], 32, 64);
  }
  if (lane < 16) {
#pragma unroll
    for (int n = 0; n < 4; ++n) pool_sh[w][n * 16 + lane] = pp[n];
  }
  __syncthreads();
  if (t < 64) {
    float p = pool_sh[0][t] + pool_sh[1][t] + pool_sh[2][t] + pool_sh[3][t];
    pool_part[((((size_t)bidx * HN + h) << 3) + lt) * 64 + t] = p;
  }
}

// Bilinear k-update GEMM: z = relu(A @ WbiT + qpart[b]) + kf -> bf16 (zbuf)
// Also emits per-(colTile,row) LN partial sums (s, s2) of the bf16 z values.
__global__ __launch_bounds__(256, 4) void gemm_bilin(
    const u16* __restrict__ A, const u16* __restrict__ BT,
    const float* __restrict__ biasB, const u16* __restrict__ resid,
    u16* __restrict__ out, float2* __restrict__ rowpart) {
  const int K = EN;
  __shared__ __align__(16) u16 SM[16384];   // As | Bs, reused as y tile
  __shared__ float bps[128], bpq[128];
  u16* As = SM;
  u16* Bs = SM + 8192;
  int t = threadIdx.x;
  int w = t >> 6, lane = t & 63;
  int wm = w >> 1, wn = w & 1;

  int bid = blockIdx.x;                 // 3072 = 8 * 384
  int swz = ((bid & 7) * 384) + (bid >> 3);
  int rowT = swz / 6, cT = swz % 6;
  int rowBase = rowT << 7;
  int colBase = cT << 7;

  int koff = (((lane & 3) ^ ((lane >> 3) & 3)) << 3);
  const u16* gA = A + (size_t)(rowBase + (w << 5) + (lane >> 2)) * K + koff;
  const u16* gB = BT + (size_t)(colBase + (w << 5) + (lane >> 2)) * K + koff;

  int lrow = lane & 15, kq = lane >> 4;
  int sOff = ((kq ^ ((lrow >> 1) & 3)) << 3);
  f32x4 acc[4][4] = {};

  u16* lA0b = As + (w << 10);
  u16* lB0b = Bs + (w << 10);
  u16* lA1b = As + 4096 + (w << 10);
  u16* lB1b = Bs + 4096 + (w << 10);

#define BIL_PREF(LA, LB, k0) \
    { gld16(gA + (k0), LA); gld16(gA + (size_t)16 * K + (k0), LA + 512); \
      gld16(gB + (k0), LB); gld16(gB + (size_t)16 * K + (k0), LB + 512); }

#define BIL_STEP(BASE) \
    { short8 af[4], bf[4]; \
      _Pragma("unroll") \
      for (int m = 0; m < 4; ++m) \
        af[m] = *(const short8*)&As[(BASE) + ((wm * 64 + m * 16 + lrow) << 5) + sOff]; \
      _Pragma("unroll") \
      for (int n = 0; n < 4; ++n) \
        bf[n] = *(const short8*)&Bs[(BASE) + ((wn * 64 + n * 16 + lrow) << 5) + sOff]; \
      _Pragma("unroll") \
      for (int m = 0; m < 4; ++m) \
        _Pragma("unroll") \
        for (int n = 0; n < 4; ++n) \
          acc[m][n] = __builtin_amdgcn_mfma_f32_16x16x32_bf16(af[m], bf[n], acc[m][n], 0, 0, 0); }

  BIL_PREF(lA0b, lB0b, 0)
#pragma unroll 1
  for (int p = 0; p < 12; ++p) {
    __syncthreads();
    BIL_PREF(lA1b, lB1b, (2 * p + 1) << 5)
    BIL_STEP(0)
    __syncthreads();
    if (p < 11) BIL_PREF(lA0b, lB0b, (2 * p + 2) << 5)
    BIL_STEP(4096)
  }
#undef BIL_PREF
#undef BIL_STEP

  __syncthreads();   // waves done reading As/Bs

  const int bidx = rowBase >> 10;
  // E1: y = relu(acc + qpart) -> SM swizzled bf16 (acc dies)
  {
    float qv[4];
#pragma unroll
    for (int n = 0; n < 4; ++n)
      qv[n] = biasB[(size_t)bidx * EN + colBase + wn * 64 + n * 16 + lrow];
#pragma unroll
    for (int m = 0; m < 4; ++m)
#pragma unroll
      for (int j = 0; j < 4; ++j) {
        int row = wm * 64 + m * 16 + kq * 4 + j;
#pragma unroll
        for (int n = 0; n < 4; ++n) {
          float y = fmaxf(acc[m][n][j] + qv[n], 0.f);
          int c = wn * 64 + n * 16 + lrow;
          int sl = c >> 3;
          int so = ((sl & 7) ^ (row & 7)) | (sl & 8);
          SM[row * 128 + (so << 3) + (c & 7)] = f2bf(y);
        }
      }
  }
  __syncthreads();

  // E2: remap (row = t>>1, half = t&1); coalesced resid read + out write;
  // accumulate LN partials of the final bf16 z values.
  {
    int row = t >> 1, ch = t & 1;
    size_t R = (size_t)rowBase + row;
    float s = 0.f, s2 = 0.f;
#pragma unroll
    for (int s8 = 0; s8 < 8; ++s8) {
      int sl = (ch << 3) + s8;
      int so = ((sl & 7) ^ (row & 7)) | (sl & 8);
      short8 yv = *(const short8*)&SM[row * 128 + (so << 3)];
      int e0 = colBase + (sl << 3);
      short8 rv = *(const short8*)&resid[R * EN + e0];
      short8 o8;
#pragma unroll
      for (int i = 0; i < 8; ++i) {
        u16 zb = f2bf(bf2f((u16)yv[i]) + bf2f((u16)rv[i]));
        o8[i] = (short)zb;
        float zf = bf2f(zb);
        s += zf; s2 += zf * zf;
      }
      *(short8*)&out[R * EN + e0] = o8;
    }
    if (ch == 1) { bps[row] = s; bpq[row] = s2; }
    __syncthreads();
    if (ch == 0)
      rowpart[(size_t)cT * (BB * LKN) + R] = make_float2(s + bps[row], s2 + bpq[row]);
  }
}

// Fused attention finish per (b,h): softmax(s) in LDS, pool->a_c, v2a, q out.
__global__ __launch_bounds__(256) void attn_fin(
    const float* __restrict__ s_in, const float* __restrict__ kmask,
    const float* __restrict__ msum, const float* __restrict__ pool_part,
    const float* __restrict__ Wac, const float* __restrict__ bac,
    const u16* __restrict__ v2, const float* __restrict__ v1,
    float* __restrict__ q_cur, float* __restrict__ feats, int slot) {
  __shared__ float as_sh[LKN];
  __shared__ float red[256];
  __shared__ float red8[16][129];
  __shared__ float pool_sh[64];
  __shared__ float ac_sh[128];
  int t = threadIdx.x;
  int h = blockIdx.x, b = blockIdx.y;
  const float* sb = s_in + (((size_t)b * HN + h) << 10);
  const float* km = kmask + (size_t)b * LKN;
  float v[4];
  float mx = -1e30f;
#pragma unroll
  for (int j = 0; j < 4; ++j) {
    int l = t * 4 + j;
    float x = sb[l];
    if (km[l] == 0.f) x = -1e9f;
    v[j] = x; mx = fmaxf(mx, x);
  }
  red[t] = mx; __syncthreads();
  for (int o = 128; o > 0; o >>= 1) { if (t < o) red[t] = fmaxf(red[t], red[t + o]); __syncthreads(); }
  float mxv = red[0];
  __syncthreads();
  float sum = 0.f;
#pragma unroll
  for (int j = 0; j < 4; ++j) { v[j] = __expf(v[j] - mxv); sum += v[j]; }
  red[t] = sum; __syncthreads();
  for (int o = 128; o > 0; o >>= 1) { if (t < o) red[t] += red[t + o]; __syncthreads(); }
  float inv = 1.f / red[0];
#pragma unroll
  for (int j = 0; j < 4; ++j) as_sh[t * 4 + j] = v[j] * inv;
  if (t < 64) {
    float p = 0.f;
    for (int lt = 0; lt < 8; ++lt)
      p += pool_part[((((size_t)b * HN + h) << 3) + lt) * 64 + t];
    pool_sh[t] = p / msum[b];
  }
  __syncthreads();
  if (t < 128) {
    float a = 0.f;
    for (int j = 0; j < 64; ++j) a += pool_sh[j] * Wac[j * HDN + t];
    ac_sh[t] = 1.f / (1.f + __expf(-(a + bac[t])));
  }
  __syncthreads();
  // v2a: 16 d-octs x 16 l-slices, short8 (16B) loads
  {
    int o = t & 15, sl = t >> 4;
    const u16* vb = v2 + ((size_t)b * LKN) * EN + h * HDN + o * 8;
    float a8[8] = {};
    for (int l = sl; l < LKN; l += 16) {
      short8 u = *(const short8*)&vb[(size_t)l * EN];
      float wgt = as_sh[l];
#pragma unroll
      for (int i = 0; i < 8; ++i) a8[i] += wgt * bf2f((u16)u[i]);
    }
#pragma unroll
    for (int i = 0; i < 8; ++i) red8[sl][o * 8 + i] = a8[i];
  }
  __syncthreads();
  if (t < 128) {
    float va = 0.f;
#pragma unroll
    for (int s = 0; s < 16; ++s) va += red8[s][t];
    size_t idx = (size_t)b * EN + h * HDN + t;
    float q = v1[idx] * va * ac_sh[t];
    q_cur[idx] = q;
    feats[(size_t)b * 3 * EN + slot * EN + h * HDN + t] = q;
  }
}

// final: out = ln(feats(B x 2304) @ Wp + bp)
__global__ __launch_bounds__(768) void final_kernel(
    const float* __restrict__ feats, const float* __restrict__ Wp,
    const float* __restrict__ bp, const float* __restrict__ g,
    const float* __restrict__ bb, float* __restrict__ outp) {
  __shared__ float fs[2304];
  __shared__ float red[24];
  __shared__ float mv[2];
  int t = threadIdx.x, b = blockIdx.x;
  fs[t] = feats[(size_t)b * 2304 + t];
  fs[t + 768] = feats[(size_t)b * 2304 + 768 + t];
  fs[t + 1536] = feats[(size_t)b * 2304 + 1536 + t];
  __syncthreads();
  float acc = 0.f;
  for (int k = 0; k < 2304; ++k) acc += fs[k] * Wp[(size_t)k * EN + t];
  float y = acc + bp[t];
  float s = y, s2 = y * y;
  for (int o = 32; o > 0; o >>= 1) { s += __shfl_down(s, o, 64); s2 += __shfl_down(s2, o, 64); }
  int wid = t >> 6, lane = t & 63;
  if (lane == 0) { red[wid] = s; red[12 + wid] = s2; }
  __syncthreads();
  if (t == 0) {
    float ts = 0.f, ts2 = 0.f;
    for (int i = 0; i < 12; ++i) { ts += red[i]; ts2 += red[12 + i]; }
    float m = ts * (1.f / EN), var = ts2 * (1.f / EN) - m * m;
    mv[0] = m; mv[1] = rsqrtf(var + EPSV);
  }
  __syncthreads();
  outp[(size_t)b * EN + t] = (y - mv[0]) * mv[1] * g[t] + bb[t];
}

// ---------------------------------------------------------------------------
extern "C" void kernel_launch(void* const* d_in, const int* in_sizes, int n_in,
                              void* d_out, int out_size, void* d_ws, size_t ws_size,
                              hipStream_t stream) {
  const float* q_feat = (const float*)d_in[0];
  const float* k_feats = (const float*)d_in[1];
  const float* q_mask = (const float*)d_in[2];
  const float* k_mask = (const float*)d_in[3];
  const float* Wq = (const float*)d_in[4];
  const float* bq = (const float*)d_in[5];
  const float* gq_g = (const float*)d_in[6];
  const float* gq_b = (const float*)d_in[7];
  const float* Wk = (const float*)d_in[8];
  const float* bk = (const float*)d_in[9];
  const float* gk_g = (const float*)d_in[10];
  const float* gk_b = (const float*)d_in[11];
  const float* Wv1 = (const float*)d_in[12];
  const float* bv1 = (const float*)d_in[13];
  const float* g1_g = (const float*)d_in[14];
  const float* g1_b = (const float*)d_in[15];
  const float* Wv2 = (const float*)d_in[16];
  const float* bv2 = (const float*)d_in[17];
  const float* g2_g = (const float*)d_in[18];
  const float* g2_b = (const float*)d_in[19];
  const float* Wab = (const float*)d_in[20];
  const float* bab = (const float*)d_in[21];
  const float* Wal = (const float*)d_in[22];
  const float* bal = (const float*)d_in[23];
  const float* Wac = (const float*)d_in[24];
  const float* bac = (const float*)d_in[25];
  const float* Wbi = (const float*)d_in[26];
  const float* bbi = (const float*)d_in[27];
  const float* lnb_g = (const float*)d_in[28];
  const float* lnb_b = (const float*)d_in[29];
  const float* Wp = (const float*)d_in[30];
  const float* bp = (const float*)d_in[31];
  const float* ln_g = (const float*)d_in[32];
  const float* ln_b = (const float*)d_in[33];
  float* out = (float*)d_out;
  (void)in_sizes; (void)n_in; (void)out_size; (void)ws_size;

  char* ws = (char*)d_ws;
  size_t off = 0;
  auto alloc = [&](size_t bytes) -> char* {
    char* p = ws + off;
    off += (bytes + 255) & ~(size_t)255;
    return p;
  };
  const size_t MK = (size_t)BB * LKN;  // 65536
  u16* kf = (u16*)alloc(MK * EN * 2);
  u16* zbuf = (u16*)alloc(MK * EN * 2);  // bilin z scratch (pre-LN)
  u16* v2b = (u16*)alloc(MK * EN * 2);
  u16* WkvT = (u16*)alloc((size_t)2 * 1536 * EN * 2);  // per layer: [Wk^T; Wv2^T] (L1: g folded)
  u16* WbiT = (u16*)alloc((size_t)EN * EN * 2);
  u16* WabT = (u16*)alloc((size_t)2 * D2N * HDN * 2);
  float* feats = (float*)alloc((size_t)BB * 3 * EN * 4);
  float* q_cur = (float*)alloc((size_t)BB * EN * 4);
  float* qp = (float*)alloc((size_t)BB * EN * 4);
  float* v1 = (float*)alloc((size_t)BB * EN * 4);
  float* qpart = (float*)alloc((size_t)BB * EN * 4);
  float* sbuf = (float*)alloc((size_t)BB * HN * LKN * 4);
  float* poolp = (float*)alloc((size_t)BB * HN * 8 * D2N * 4);
  float* msum = (float*)alloc((size_t)BB * 4);
  float2* rowpart = (float2*)alloc((size_t)6 * MK * 8);
  float* uvec = (float*)alloc(1536 * 4);
  float* vbvec = (float*)alloc(1536 * 4);

  // ---- fused prep (conv + 5x transpose + Wab transpose + uv + poolq + msum)
  prep_kernel<<<NB_PREP, 256, 0, stream>>>(
      k_feats, kf, Wk, Wv2, Wbi, lnb_g, WkvT, WbiT, Wab, WabT,
      lnb_b, bk + EN, bv2 + EN, uvec, vbvec,
      q_feat, q_mask, q_cur, feats, k_mask, msum);

  // ---- layer 0
  qside2_kernel<<<dim3(BB, 2), 768, 0, stream>>>(
      q_cur, Wq, bq, gq_g, gq_b, qp,
      Wv1, bv1, g1_g, g1_b, v1, nullptr, nullptr, nullptr);
  gemm_proj<false><<<6144, 256, 0, stream>>>(
      kf, WkvT, bk, gk_g, gk_b, qp,
      bv2, g2_g, g2_b, v2b,
      WabT, bab, Wal, bal, k_mask, sbuf, poolp,
      nullptr, nullptr, nullptr);
  attn_fin<<<dim3(HN, BB), 256, 0, stream>>>(
      sbuf, k_mask, msum, poolp, Wac, bac, v2b, v1, q_cur, feats, 1);

  // ---- layer 1: bilin -> (z, LN partials); proj consumes z with LN applied
  //      algebraically (g folded into W, u/vb correction, per-block rowstat).
  qside2_kernel<<<dim3(BB, 3), 768, 0, stream>>>(
      q_cur, Wq + (size_t)EN * EN, bq + EN, gq_g + EN, gq_b + EN, qp,
      Wv1 + (size_t)EN * EN, bv1 + EN, g1_g + EN, g1_b + EN, v1,
      Wbi, bbi, qpart);
  gemm_bilin<<<3072, 256, 0, stream>>>(kf, WbiT, qpart, kf, zbuf, rowpart);
  gemm_proj<true><<<6144, 256, 0, stream>>>(
      zbuf, WkvT + (size_t)1536 * EN, bk + EN, gk_g + EN, gk_b + EN, qp,
      bv2 + EN, g2_g + EN, g2_b + EN, v2b,
      WabT + (size_t)D2N * HDN, bab + D2N, Wal + D2N, bal + 1, k_mask, sbuf, poolp,
      rowpart, uvec, vbvec);
  attn_fin<<<dim3(HN, BB), 256, 0, stream>>>(
      sbuf, k_mask, msum, poolp, Wac + (size_t)D2N * HDN, bac + HDN, v2b, v1, q_cur, feats, 2);

  final_kernel<<<BB, EN, 0, stream>>>(feats, Wp, bp, ln_g, ln_b, out);
}